// Round 3
// baseline (625.937 us; speedup 1.0000x reference)
//
#include <hip/hip_runtime.h>
#include <stdint.h>

#define PHM      4
#define IN_FEATS 2048
#define OUT_FEATS 8192
#define TOKENS   8192
#define IN_PER   512    // IN_FEATS / PHM
#define OUT_PER  2048   // OUT_FEATS / PHM

typedef __attribute__((ext_vector_type(8)))  short short8;
typedef __attribute__((ext_vector_type(16))) float f32x16;
typedef __attribute__((ext_vector_type(8)))  unsigned short u16x8;

// round-to-nearest-even fp32 -> bf16 (inputs are finite Gaussians, no NaN path)
__device__ inline unsigned short f2bf(float f) {
    unsigned int u = __builtin_bit_cast(unsigned int, f);
    u += 0x7fffu + ((u >> 16) & 1u);
    return (unsigned short)(u >> 16);
}

// ---------------- kernel 1: x fp32 -> bf16, 8 elem/thread ----------------
__global__ void cvt_x_kernel(const float* __restrict__ x,
                             unsigned short* __restrict__ xb) {
    int i = blockIdx.x * blockDim.x + threadIdx.x;  // one per 8 elements
    const float4* x4 = (const float4*)x;
    float4 v0 = x4[2 * i];
    float4 v1 = x4[2 * i + 1];
    u16x8 o;
    o[0] = f2bf(v0.x); o[1] = f2bf(v0.y); o[2] = f2bf(v0.z); o[3] = f2bf(v0.w);
    o[4] = f2bf(v1.x); o[5] = f2bf(v1.y); o[6] = f2bf(v1.z); o[7] = f2bf(v1.w);
    *(u16x8*)(xb + 8 * (size_t)i) = o;
}

// ---------------- kernel 2: build Ht[n][k] = sum_i rule[i,a,kq]*W[i,c,p] ----
__global__ void build_ht_kernel(const float* __restrict__ rule,  // [4][4][4] (i,a,kq)
                                const float* __restrict__ W,     // [4][512][2048]
                                unsigned short* __restrict__ Ht) // [8192][2048] bf16
{
    __shared__ float lds[PHM][32][65];  // +1 pad: conflict-free column reads
    const int tid = threadIdx.x;
    const int c0 = blockIdx.x * 32;
    const int p0 = blockIdx.y * 64;

    #pragma unroll
    for (int it = 0; it < 32; ++it) {
        int idx = it * 256 + tid;        // 0..8191
        int pp = idx & 63;
        int cc = (idx >> 6) & 31;
        int i  = idx >> 11;
        lds[i][cc][pp] = W[((size_t)(i * IN_PER + c0 + cc)) * OUT_PER + p0 + pp];
    }
    __syncthreads();

    const int pp = tid >> 2;         // 0..63
    const int j0 = (tid & 3) * 8;    // c-chunk of 8
    float w[PHM][8];
    #pragma unroll
    for (int i = 0; i < PHM; ++i)
        #pragma unroll
        for (int j = 0; j < 8; ++j)
            w[i][j] = lds[i][j0 + j][pp];

    #pragma unroll
    for (int a = 0; a < PHM; ++a) {
        #pragma unroll
        for (int kq = 0; kq < PHM; ++kq) {
            float r0 = rule[(0 * PHM + a) * PHM + kq];
            float r1 = rule[(1 * PHM + a) * PHM + kq];
            float r2 = rule[(2 * PHM + a) * PHM + kq];
            float r3 = rule[(3 * PHM + a) * PHM + kq];
            u16x8 o;
            #pragma unroll
            for (int j = 0; j < 8; ++j) {
                float v = r0 * w[0][j] + r1 * w[1][j] + r2 * w[2][j] + r3 * w[3][j];
                o[j] = f2bf(v);
            }
            size_t n = (size_t)(kq * OUT_PER + p0 + pp);
            *(u16x8*)(Ht + n * IN_FEATS + a * IN_PER + c0 + j0) = o;  // 16B coalesced
        }
    }
}

// ---------------- kernel 3: C[M][N] = A[M][K] * B[N][K]^T + bias ------------
// Round-6 == Round-5 resubmit (round-5 bench died at container level; source
// audited for OOB/hang/deadlock — none; infra timing showed 2100s pushes).
// 256x256 tile, 8 waves (2x4), wave tile 128x64 as 4x2 of
// mfma_f32_32x32x16_bf16.  BK=64, 2 phases/tile of 16 MFMA each.
// LDS: 2 dbuf x (A 32KB + B 32KB) = 128 KiB, row-major [256][64] bf16 with
// full-row XOR swizzle: 16B chunk c of row r stored at slot c^(r&7).
//   - read: wave's b128 at (r=base+lm, c=2ks+kh) hits every bank-quad
//     exactly 8x (data-width minimum) -> zero excess conflicts.
//   - stage: linear gload_lds dest + inverse-permuted global source:
//     each 8-lane group reads one full contiguous 128B row (coalesced).
// Counted pipeline via early region release: B-region of buf[t&1] is dead
// after phase-1 reads, A-region after phase-2 reads; tile t+2's B/A stages
// issue right after each phase's read-barrier into those regions.  Boundary
// wait = vmcnt(8): keeps t+2's 8 loads in flight, guarantees (by count)
// t+1's older 8 are retired.  No XCD swizzle (round-4's hurt L2 locality).
#define BM 256
#define BN 256
#define BK 64
#define NT (IN_FEATS / BK)       // 32 K-tiles

__device__ inline void gload16(const unsigned short* g, unsigned short* l) {
    __builtin_amdgcn_global_load_lds(
        (const __attribute__((address_space(1))) unsigned int*)g,
        (__attribute__((address_space(3))) unsigned int*)l,
        16, 0, 0);
}

__device__ inline void barrier_fenced() {
    asm volatile("" ::: "memory");
    __builtin_amdgcn_s_barrier();
    asm volatile("" ::: "memory");
}

__global__ __launch_bounds__(512, 2) void gemm_bt_kernel(
    const unsigned short* __restrict__ A,   // [M][K] bf16 (x)
    const unsigned short* __restrict__ B,   // [N][K] bf16 (Ht)
    const float* __restrict__ bias,         // [N]
    float* __restrict__ C)                  // [M][N] fp32
{
    constexpr int N = OUT_FEATS, K = IN_FEATS;
    // [dbuf 2][ A 16384 | B 16384 ] ushorts = 128 KiB
    __shared__ unsigned short LDS[65536];

    const int tid  = threadIdx.x;
    const int wave = tid >> 6;
    const int lane = tid & 63;
    const int lm   = lane & 31;              // MFMA fragment row
    const int kh   = lane >> 5;              // which 8-k half of each k16

    const int bn = blockIdx.x;               // natural order (no XCD swizzle)
    const int bm = blockIdx.y;

    const int wm = (wave >> 2) * 128;        // wave's 128-row band of C
    const int wn = (wave & 3) * 64;          // wave's 64-col band of C

    // ---- swizzled read offsets (ushort units): slot(c,r) = c ^ (r&7) ----
    // r&7 == lm&7 for both A and B reader rows (wm, wn, 32*frag all %8==0)
    int aoff[4], boff[4];
    #pragma unroll
    for (int ks = 0; ks < 4; ++ks) {
        int slot = ((2 * ks + kh) ^ (lm & 7)) * 8;
        aoff[ks] = (wm + lm) * 64 + slot;
        boff[ks] = 16384 + (wn + lm) * 64 + slot;
    }

    // ---- staging maps: LDS chunk q = i*512 + wave*64 + lane (linear dest);
    // q -> row = q>>3, slot = q&7; content = global chunk slot^(row&7) ----
    const int srow = wave * 8 + (lane >> 3);                 // + i*64
    const int schk = (lane & 7) ^ ((lane >> 3) & 7);
    const unsigned short* AgS = A + (size_t)(bm * BM + srow) * K + schk * 8;
    const unsigned short* BgS = B + (size_t)(bn * BN + srow) * K + schk * 8;
    unsigned short* const Ad = LDS + wave * 512;             // + db + i*4096
    unsigned short* const Bd = LDS + 16384 + wave * 512;

    // ---- prologue: tile0 -> dbuf0, tile1 -> dbuf1; wait for tile0 ----
    #pragma unroll
    for (int i = 0; i < 4; ++i) gload16(AgS + (size_t)i * 64 * K,      Ad + i * 4096);
    #pragma unroll
    for (int i = 0; i < 4; ++i) gload16(BgS + (size_t)i * 64 * K,      Bd + i * 4096);
    #pragma unroll
    for (int i = 0; i < 4; ++i) gload16(AgS + 64 + (size_t)i * 64 * K, Ad + 32768 + i * 4096);
    #pragma unroll
    for (int i = 0; i < 4; ++i) gload16(BgS + 64 + (size_t)i * 64 * K, Bd + 32768 + i * 4096);
    asm volatile("s_waitcnt vmcnt(8)" ::: "memory");
    barrier_fenced();

    f32x16 acc[4][2] = {};   // [m-frag 0..3][n-frag 0..1]
    short8 a[2][4], b[2][4];

    #pragma unroll 1
    for (int t = 0; t < NT; ++t) {
        const int  db   = (t & 1) << 15;     // read buffer (ushort offset)
        const int  koff = (t + 2) * BK;      // k-offset of tile being staged
        const bool st   = (t + 2) < NT;

        // ======== phase 1: read a(mf0,1) + all b ; then stage B(t+2) ======
        #pragma unroll
        for (int mf = 0; mf < 2; ++mf)
            #pragma unroll
            for (int ks = 0; ks < 4; ++ks)
                a[mf][ks] = *(const short8*)(LDS + db + aoff[ks] + mf * 2048);
        #pragma unroll
        for (int nf = 0; nf < 2; ++nf)
            #pragma unroll
            for (int ks = 0; ks < 4; ++ks)
                b[nf][ks] = *(const short8*)(LDS + db + boff[ks] + nf * 2048);
        barrier_fenced();                    // all waves' B reads issued/served
        asm volatile("s_waitcnt lgkmcnt(0)" ::: "memory");
        __builtin_amdgcn_sched_barrier(0);
        if (st) {                            // B-region of buf[t&1] now dead
            #pragma unroll
            for (int i = 0; i < 4; ++i)
                gload16(BgS + koff + (size_t)i * 64 * K, Bd + db + i * 4096);
        }
        __builtin_amdgcn_s_setprio(1);
        #pragma unroll
        for (int ks = 0; ks < 4; ++ks)
            #pragma unroll
            for (int mf = 0; mf < 2; ++mf)
                #pragma unroll
                for (int nf = 0; nf < 2; ++nf)
                    acc[mf][nf] = __builtin_amdgcn_mfma_f32_32x32x16_bf16(
                        a[mf][ks], b[nf][ks], acc[mf][nf], 0, 0, 0);
        __builtin_amdgcn_s_setprio(0);
        barrier_fenced();

        // ======== phase 2: read a(mf2,3) ; then stage A(t+2) ==============
        #pragma unroll
        for (int mf = 0; mf < 2; ++mf)
            #pragma unroll
            for (int ks = 0; ks < 4; ++ks)
                a[mf][ks] = *(const short8*)(LDS + db + aoff[ks] + (2 + mf) * 2048);
        barrier_fenced();                    // all waves' A reads issued/served
        asm volatile("s_waitcnt lgkmcnt(0)" ::: "memory");
        __builtin_amdgcn_sched_barrier(0);
        if (st) {                            // A-region of buf[t&1] now dead
            #pragma unroll
            for (int i = 0; i < 4; ++i)
                gload16(AgS + koff + (size_t)i * 64 * K, Ad + db + i * 4096);
        }
        __builtin_amdgcn_s_setprio(1);
        #pragma unroll
        for (int ks = 0; ks < 4; ++ks)
            #pragma unroll
            for (int mf = 0; mf < 2; ++mf)
                #pragma unroll
                for (int nf = 0; nf < 2; ++nf)
                    acc[2 + mf][nf] = __builtin_amdgcn_mfma_f32_32x32x16_bf16(
                        a[mf][ks], b[nf][ks], acc[2 + mf][nf], 0, 0, 0);
        __builtin_amdgcn_s_setprio(0);
        // boundary: retire everything older than t+2's 8 loads (counted);
        // tail (t>=30): full drain (t+1 staged one tile ago).
        if (t < NT - 2) asm volatile("s_waitcnt vmcnt(8)" ::: "memory");
        else            asm volatile("s_waitcnt vmcnt(0)" ::: "memory");
        barrier_fenced();
    }

    // epilogue: 32x32 C/D layout col=lane&31, row=(reg&3)+8*(reg>>2)+4*(lane>>5)
    const int cn = lm;
    const int rb = 4 * kh;
    #pragma unroll
    for (int j = 0; j < 2; ++j) {
        const int col = bn * BN + wn + j * 32 + cn;
        const float bv = bias[col];
        #pragma unroll
        for (int i = 0; i < 4; ++i) {
            const int row0 = bm * BM + wm + i * 32 + rb;
            #pragma unroll
            for (int reg = 0; reg < 16; ++reg) {
                int row = row0 + (reg & 3) + 8 * (reg >> 2);
                C[(size_t)row * N + col] = acc[i][j][reg] + bv;
            }
        }
    }
}

extern "C" void kernel_launch(void* const* d_in, const int* in_sizes, int n_in,
                              void* d_out, int out_size, void* d_ws, size_t ws_size,
                              hipStream_t stream) {
    const float* x    = (const float*)d_in[0];   // [8192][2048]
    const float* rule = (const float*)d_in[1];   // [4][4][4]
    const float* W    = (const float*)d_in[2];   // [4][512][2048]
    const float* b    = (const float*)d_in[3];   // [8192]
    float* y = (float*)d_out;                    // [8192][8192]

    unsigned short* xb = (unsigned short*)d_ws;                       // 32 MB
    unsigned short* Ht = (unsigned short*)((char*)d_ws +
                         (size_t)TOKENS * IN_FEATS * sizeof(unsigned short)); // 32 MB

    cvt_x_kernel<<<(TOKENS * IN_FEATS) / 8 / 256, 256, 0, stream>>>(x, xb);
    build_ht_kernel<<<dim3(IN_PER / 32, OUT_PER / 64), 256, 0, stream>>>(rule, W, Ht);
    gemm_bt_kernel<<<dim3(OUT_FEATS / BN, TOKENS / BM), 512, 0, stream>>>(xb, Ht, b, y);
}

// Round 4
// 544.807 us; speedup vs baseline: 1.1489x; 1.1489x over previous
//
#include <hip/hip_runtime.h>
#include <stdint.h>

#define PHM      4
#define IN_FEATS 2048
#define OUT_FEATS 8192
#define TOKENS   8192
#define IN_PER   512    // IN_FEATS / PHM
#define OUT_PER  2048   // OUT_FEATS / PHM

typedef __attribute__((ext_vector_type(8)))  short short8;
typedef __attribute__((ext_vector_type(4)))  float f32x4;
typedef __attribute__((ext_vector_type(8)))  unsigned short u16x8;

// round-to-nearest-even fp32 -> bf16 (inputs are finite Gaussians, no NaN path)
__device__ inline unsigned short f2bf(float f) {
    unsigned int u = __builtin_bit_cast(unsigned int, f);
    u += 0x7fffu + ((u >> 16) & 1u);
    return (unsigned short)(u >> 16);
}

// ---------------- kernel 1: x fp32 -> bf16, 8 elem/thread ----------------
__global__ void cvt_x_kernel(const float* __restrict__ x,
                             unsigned short* __restrict__ xb) {
    int i = blockIdx.x * blockDim.x + threadIdx.x;  // one per 8 elements
    const float4* x4 = (const float4*)x;
    float4 v0 = x4[2 * i];
    float4 v1 = x4[2 * i + 1];
    u16x8 o;
    o[0] = f2bf(v0.x); o[1] = f2bf(v0.y); o[2] = f2bf(v0.z); o[3] = f2bf(v0.w);
    o[4] = f2bf(v1.x); o[5] = f2bf(v1.y); o[6] = f2bf(v1.z); o[7] = f2bf(v1.w);
    *(u16x8*)(xb + 8 * (size_t)i) = o;
}

// ---------------- kernel 2: build Ht[n][k] = sum_i rule[i,a,kq]*W[i,c,p] ----
__global__ void build_ht_kernel(const float* __restrict__ rule,  // [4][4][4] (i,a,kq)
                                const float* __restrict__ W,     // [4][512][2048]
                                unsigned short* __restrict__ Ht) // [8192][2048] bf16
{
    __shared__ float lds[PHM][32][65];  // +1 pad: conflict-free column reads
    const int tid = threadIdx.x;
    const int c0 = blockIdx.x * 32;
    const int p0 = blockIdx.y * 64;

    #pragma unroll
    for (int it = 0; it < 32; ++it) {
        int idx = it * 256 + tid;        // 0..8191
        int pp = idx & 63;
        int cc = (idx >> 6) & 31;
        int i  = idx >> 11;
        lds[i][cc][pp] = W[((size_t)(i * IN_PER + c0 + cc)) * OUT_PER + p0 + pp];
    }
    __syncthreads();

    const int pp = tid >> 2;         // 0..63
    const int j0 = (tid & 3) * 8;    // c-chunk of 8
    float w[PHM][8];
    #pragma unroll
    for (int i = 0; i < PHM; ++i)
        #pragma unroll
        for (int j = 0; j < 8; ++j)
            w[i][j] = lds[i][j0 + j][pp];

    #pragma unroll
    for (int a = 0; a < PHM; ++a) {
        #pragma unroll
        for (int kq = 0; kq < PHM; ++kq) {
            float r0 = rule[(0 * PHM + a) * PHM + kq];
            float r1 = rule[(1 * PHM + a) * PHM + kq];
            float r2 = rule[(2 * PHM + a) * PHM + kq];
            float r3 = rule[(3 * PHM + a) * PHM + kq];
            u16x8 o;
            #pragma unroll
            for (int j = 0; j < 8; ++j) {
                float v = r0 * w[0][j] + r1 * w[1][j] + r2 * w[2][j] + r3 * w[3][j];
                o[j] = f2bf(v);
            }
            size_t n = (size_t)(kq * OUT_PER + p0 + pp);
            *(u16x8*)(Ht + n * IN_FEATS + a * IN_PER + c0 + j0) = o;  // 16B coalesced
        }
    }
}

// ---------------- kernel 3: C[M][N] = A[M][K] * B[N][K]^T + bias ------------
// Round-7: faithful m201 8-phase port.  256x256 tile, 8 waves, BK=64,
// mfma_f32_16x16x32_bf16.  Wave output = rows {wm..wm+63}U{wm+128..wm+191}
// (wm=(wave>>2)*64), cols {wn..wn+31}U{wn+128..wn+159} (wn=(wave&3)*32) --
// interleaved bands so phase reads align with 128-row staging halves.
// 4 phases per K-tile, 16 MFMA each (one 64x32 C-quadrant x K=64):
//   P1: read A-mh0(8 b128)+B-nh0(4); P2: read B-nh1(4); P3: read A-mh1(8);
//   P4: no reads.  Each phase: {vmcnt(8); ds_reads; stage 1 half-tile
//   (2 gload_lds); barrier; lgkmcnt(0); sched_barrier; setprio(1); 16 MFMA;
//   setprio(0); barrier}.  8 phases process 2 K-tiles (dbuf0, dbuf1).
// Staging ledger (verified): 1 half/phase, consumer at phase k uses the half
// staged at k-6; uniform vmcnt(8) at (k-1)-top retires stage(k-5) for every
// wave, so barrier end-(k-1) guarantees all waves' stage(k-6) landed.
// Prologue stages 7 halves; tail iter uses vmcnt(4)/(2)/(0).
// LDS swizzle: slot = chunk ^ (row&7) in each [128][64]bf16 half (uniform
// 8 lanes/bank = b128 floor); linear gload dest + inverse-permuted source.
#define BM 256
#define BN 256
#define BK 64
#define NT (IN_FEATS / BK)       // 32 K-tiles, 16 iterations

__device__ inline void gload16(const unsigned short* g, unsigned short* l) {
    __builtin_amdgcn_global_load_lds(
        (const __attribute__((address_space(1))) unsigned int*)g,
        (__attribute__((address_space(3))) unsigned int*)l,
        16, 0, 0);
}

#define WAITV(N) asm volatile("s_waitcnt vmcnt(" #N ")" ::: "memory")
#define LGKM0    asm volatile("s_waitcnt lgkmcnt(0)" ::: "memory")
#define FENCE    asm volatile("" ::: "memory")
#define SBAR     do { FENCE; __builtin_amdgcn_s_barrier(); FENCE; } while (0)

__global__ __launch_bounds__(512, 2) void gemm_bt_kernel(
    const unsigned short* __restrict__ A,   // [M][K] bf16 (x)
    const unsigned short* __restrict__ B,   // [N][K] bf16 (Ht)
    const float* __restrict__ bias,         // [N]
    float* __restrict__ C)                  // [M][N] fp32
{
    constexpr int N = OUT_FEATS, K = IN_FEATS;
    // [dbuf 2][ A 16384 | B 16384 ] ushorts = 128 KiB; halves of 8192 (128 rows)
    __shared__ unsigned short LDS[65536];

    const int tid  = threadIdx.x;
    const int wave = tid >> 6;
    const int lane = tid & 63;
    const int lm16 = lane & 15;              // MFMA fragment row/col
    const int l47  = lane >> 4;              // 0..3: k-quarter selector

    const int bn = blockIdx.x;
    const int bm = blockIdx.y;

    const int wm = (wave >> 2) * 64;         // wave m-band base (interleaved)
    const int wn = (wave & 3) * 32;          // wave n-band base (interleaved)

    // ---- swizzled ds_read offsets (ushort units): slot = chunk ^ (row&7),
    // row&7 == lane&7 (all frag row bases are multiples of 16) ----
    const int aB  = (wm + lm16) * 64;                    // + FB + f*1024 + sc
    const int bB  = 16384 + (wn + lm16) * 64;
    const int sc0 = ((l47      ^ (lane & 7))) * 8;       // k2=0 chunk = l47
    const int sc1 = (((4 + l47) ^ (lane & 7))) * 8;      // k2=1 chunk = 4+l47

    // ---- staging: half-tile = 128 rows x 64 k = 1024 chunks; thread covers
    // chunks {tid, 512+tid}; row = q>>3, slot = q&7, content chunk = slot^(row&7)
    const int srow = tid >> 3;                               // 0..63 (+64 for load 1)
    const int schk = (lane & 7) ^ ((lane >> 3) & 7);
    const unsigned short* AgS = A + (size_t)(bm * BM + srow) * K + schk * 8;
    const unsigned short* BgS = B + (size_t)(bn * BN + srow) * K + schk * 8;

    // STG_X(db, h, T): stage half h of operand X, K-tile T, into dbuf db
    #define STG_A(db, h, T) do { \
        gload16(AgS + (size_t)((h) * 128)      * K + (T) * 64, LDS + (db) + (h) * 8192        + wave * 512); \
        gload16(AgS + (size_t)((h) * 128 + 64) * K + (T) * 64, LDS + (db) + (h) * 8192 + 4096 + wave * 512); } while (0)
    #define STG_B(db, h, T) do { \
        gload16(BgS + (size_t)((h) * 128)      * K + (T) * 64, LDS + 16384 + (db) + (h) * 8192        + wave * 512); \
        gload16(BgS + (size_t)((h) * 128 + 64) * K + (T) * 64, LDS + 16384 + (db) + (h) * 8192 + 4096 + wave * 512); } while (0)

    #define RD_A(D, FB) do { _Pragma("unroll") \
        for (int ff = 0; ff < 4; ++ff) { \
            a[ff][0] = *(const short8*)(LDS + (D) + aB + (FB) + ff * 1024 + sc0); \
            a[ff][1] = *(const short8*)(LDS + (D) + aB + (FB) + ff * 1024 + sc1); } } while (0)
    #define RD_B01(D) do { _Pragma("unroll") \
        for (int g = 0; g < 2; ++g) { \
            b[g][0] = *(const short8*)(LDS + (D) + bB + g * 1024 + sc0); \
            b[g][1] = *(const short8*)(LDS + (D) + bB + g * 1024 + sc1); } } while (0)
    #define RD_B23(D) do { _Pragma("unroll") \
        for (int g = 0; g < 2; ++g) { \
            b[2 + g][0] = *(const short8*)(LDS + (D) + bB + 8192 + g * 1024 + sc0); \
            b[2 + g][1] = *(const short8*)(LDS + (D) + bB + 8192 + g * 1024 + sc1); } } while (0)

    #define MM(FB, GB) do { _Pragma("unroll") \
        for (int k2 = 0; k2 < 2; ++k2) { _Pragma("unroll") \
            for (int ff = 0; ff < 4; ++ff) { _Pragma("unroll") \
                for (int g = 0; g < 2; ++g) \
                    acc[(FB) + ff][(GB) + g] = __builtin_amdgcn_mfma_f32_16x16x32_bf16( \
                        a[ff][k2], b[(GB) + g][k2], acc[(FB) + ff][(GB) + g], 0, 0, 0); } } } while (0)

    #define PH_MID do { SBAR; LGKM0; __builtin_amdgcn_sched_barrier(0); \
                        __builtin_amdgcn_s_setprio(1); } while (0)
    #define PH_END do { __builtin_amdgcn_s_setprio(0); SBAR; } while (0)

    // ---- prologue: 7 halves in consumption order (A-h1(t1) deferred to P1)
    STG_A(0, 0, 0);  STG_B(0, 0, 0);  STG_B(0, 1, 0);  STG_A(0, 1, 0);
    STG_A(32768, 0, 1);  STG_B(32768, 0, 1);  STG_B(32768, 1, 1);
    WAITV(8);                         // retires A-h0(0), B-h0(0), B-h1(0)
    SBAR;

    f32x4 acc[8][4] = {};             // [m-frag][n-frag]
    short8 a[4][2], b[4][2];

    #pragma unroll 1
    for (int j = 0; j < NT / 2 - 1; ++j) {   // iters 0..14: tiles 2j (dbuf0), 2j+1 (dbuf1)
        const int t2 = 2 * j + 2, t3 = 2 * j + 3;
        // P1
        WAITV(8); RD_A(0, 0); RD_B01(0); STG_A(32768, 1, 2 * j + 1);
        PH_MID; MM(0, 0); PH_END;
        // P2
        WAITV(8); RD_B23(0); STG_A(0, 0, t2);
        PH_MID; MM(0, 2); PH_END;
        // P3
        WAITV(8); RD_A(0, 8192); STG_B(0, 0, t2);
        PH_MID; MM(4, 0); PH_END;
        // P4
        WAITV(8); STG_B(0, 1, t2);
        PH_MID; MM(4, 2); PH_END;
        // P5
        WAITV(8); RD_A(32768, 0); RD_B01(32768); STG_A(0, 1, t2);
        PH_MID; MM(0, 0); PH_END;
        // P6
        WAITV(8); RD_B23(32768); STG_A(32768, 0, t3);
        PH_MID; MM(0, 2); PH_END;
        // P7
        WAITV(8); RD_A(32768, 8192); STG_B(32768, 0, t3);
        PH_MID; MM(4, 0); PH_END;
        // P8
        WAITV(8); STG_B(32768, 1, t3);
        PH_MID; MM(4, 2); PH_END;
    }

    // ---- tail iter (tiles NT-2 -> dbuf0, NT-1 -> dbuf1): only P1 stages ----
    // P1
    WAITV(8); RD_A(0, 0); RD_B01(0); STG_A(32768, 1, NT - 1);
    PH_MID; MM(0, 0); PH_END;
    // P2
    WAITV(8); RD_B23(0);
    PH_MID; MM(0, 2); PH_END;
    // P3
    WAITV(8); RD_A(0, 8192);
    PH_MID; MM(4, 0); PH_END;
    // P4
    WAITV(4);
    PH_MID; MM(4, 2); PH_END;
    // P5
    WAITV(2); RD_A(32768, 0); RD_B01(32768);
    PH_MID; MM(0, 0); PH_END;
    // P6
    WAITV(0); RD_B23(32768);
    PH_MID; MM(0, 2); PH_END;
    // P7
    RD_A(32768, 8192);
    PH_MID; MM(4, 0); PH_END;
    // P8
    PH_MID; MM(4, 2); PH_END;

    // epilogue: 16x16x32 C/D layout col=lane&15, row=(lane>>4)*4+reg
    #pragma unroll
    for (int g = 0; g < 4; ++g) {
        const int col = bn * BN + wn + (g >> 1) * 128 + (g & 1) * 16 + lm16;
        const float bv = bias[col];
        #pragma unroll
        for (int f = 0; f < 8; ++f) {
            const int row0 = bm * BM + wm + (f >> 2) * 128 + (f & 3) * 16 + l47 * 4;
            #pragma unroll
            for (int r = 0; r < 4; ++r)
                C[(size_t)(row0 + r) * N + col] = acc[f][g][r] + bv;
        }
    }
    #undef STG_A
    #undef STG_B
    #undef RD_A
    #undef RD_B01
    #undef RD_B23
    #undef MM
    #undef PH_MID
    #undef PH_END
}

extern "C" void kernel_launch(void* const* d_in, const int* in_sizes, int n_in,
                              void* d_out, int out_size, void* d_ws, size_t ws_size,
                              hipStream_t stream) {
    const float* x    = (const float*)d_in[0];   // [8192][2048]
    const float* rule = (const float*)d_in[1];   // [4][4][4]
    const float* W    = (const float*)d_in[2];   // [4][512][2048]
    const float* b    = (const float*)d_in[3];   // [8192]
    float* y = (float*)d_out;                    // [8192][8192]

    unsigned short* xb = (unsigned short*)d_ws;                       // 32 MB
    unsigned short* Ht = (unsigned short*)((char*)d_ws +
                         (size_t)TOKENS * IN_FEATS * sizeof(unsigned short)); // 32 MB

    cvt_x_kernel<<<(TOKENS * IN_FEATS) / 8 / 256, 256, 0, stream>>>(x, xb);
    build_ht_kernel<<<dim3(IN_PER / 32, OUT_PER / 64), 256, 0, stream>>>(rule, W, Ht);
    gemm_bt_kernel<<<dim3(OUT_FEATS / BN, TOKENS / BM), 512, 0, stream>>>(xb, Ht, b, y);
}

// Round 5
// 524.717 us; speedup vs baseline: 1.1929x; 1.0383x over previous
//
#include <hip/hip_runtime.h>
#include <stdint.h>

#define PHM      4
#define IN_FEATS 2048
#define OUT_FEATS 8192
#define TOKENS   8192
#define IN_PER   512    // IN_FEATS / PHM
#define OUT_PER  2048   // OUT_FEATS / PHM

typedef __attribute__((ext_vector_type(8)))  short short8;
typedef __attribute__((ext_vector_type(4)))  float f32x4;
typedef __attribute__((ext_vector_type(8)))  unsigned short u16x8;

// round-to-nearest-even fp32 -> bf16 (inputs are finite Gaussians, no NaN path)
__device__ inline unsigned short f2bf(float f) {
    unsigned int u = __builtin_bit_cast(unsigned int, f);
    u += 0x7fffu + ((u >> 16) & 1u);
    return (unsigned short)(u >> 16);
}

// ---------------- kernel 1+2 fused: build Ht (blocks 0..511) and
// cvt x->bf16 (blocks 512..8703).  Independent data; fusion overlaps the
// two small memory-bound ops and saves one launch serialization. ----------
#define BUILD_BLOCKS 512                 // (IN_PER/32) * (OUT_PER/64)
#define CVT_BLOCKS   8192                // TOKENS*IN_FEATS / 8 / 256

__global__ void prep_kernel(const float* __restrict__ x,
                            unsigned short* __restrict__ xb,
                            const float* __restrict__ rule,  // [4][4][4] (i,a,kq)
                            const float* __restrict__ W,     // [4][512][2048]
                            unsigned short* __restrict__ Ht) // [8192][2048] bf16
{
    __shared__ float lds[PHM][32][65];  // +1 pad: conflict-free column reads
    const int tid = threadIdx.x;

    if (blockIdx.x >= BUILD_BLOCKS) {
        // ---- cvt branch: x fp32 -> bf16, 8 elem/thread ----
        int i = (blockIdx.x - BUILD_BLOCKS) * blockDim.x + tid;
        const float4* x4 = (const float4*)x;
        float4 v0 = x4[2 * i];
        float4 v1 = x4[2 * i + 1];
        u16x8 o;
        o[0] = f2bf(v0.x); o[1] = f2bf(v0.y); o[2] = f2bf(v0.z); o[3] = f2bf(v0.w);
        o[4] = f2bf(v1.x); o[5] = f2bf(v1.y); o[6] = f2bf(v1.z); o[7] = f2bf(v1.w);
        *(u16x8*)(xb + 8 * (size_t)i) = o;
        return;
    }

    // ---- build branch: Ht[n][k] = sum_i rule[i,a,kq]*W[i,c,p] ----
    const int c0 = (blockIdx.x & 15) * 32;   // IN_PER/32 = 16
    const int p0 = (blockIdx.x >> 4) * 64;

    #pragma unroll
    for (int it = 0; it < 32; ++it) {
        int idx = it * 256 + tid;        // 0..8191
        int pp = idx & 63;
        int cc = (idx >> 6) & 31;
        int i  = idx >> 11;
        lds[i][cc][pp] = W[((size_t)(i * IN_PER + c0 + cc)) * OUT_PER + p0 + pp];
    }
    __syncthreads();

    const int pp = tid >> 2;         // 0..63
    const int j0 = (tid & 3) * 8;    // c-chunk of 8
    float w[PHM][8];
    #pragma unroll
    for (int i = 0; i < PHM; ++i)
        #pragma unroll
        for (int j = 0; j < 8; ++j)
            w[i][j] = lds[i][j0 + j][pp];

    #pragma unroll
    for (int a = 0; a < PHM; ++a) {
        #pragma unroll
        for (int kq = 0; kq < PHM; ++kq) {
            float r0 = rule[(0 * PHM + a) * PHM + kq];
            float r1 = rule[(1 * PHM + a) * PHM + kq];
            float r2 = rule[(2 * PHM + a) * PHM + kq];
            float r3 = rule[(3 * PHM + a) * PHM + kq];
            u16x8 o;
            #pragma unroll
            for (int j = 0; j < 8; ++j) {
                float v = r0 * w[0][j] + r1 * w[1][j] + r2 * w[2][j] + r3 * w[3][j];
                o[j] = f2bf(v);
            }
            size_t n = (size_t)(kq * OUT_PER + p0 + pp);
            *(u16x8*)(Ht + n * IN_FEATS + a * IN_PER + c0 + j0) = o;  // 16B coalesced
        }
    }
}

// ---------------- kernel 3: C[M][N] = A[M][K] * B[N][K]^T + bias ------------
// Round-8: round-7's verified 8-phase structure (256x256, 8 waves, BK=64,
// mfma_f32_16x16x32_bf16, exact conflict-free swizzle, MfmaUtil 47.5%,
// bank-conflicts 0) with TEMPLATE-CONFORMANT waits: counted vmcnt at
// phases 4 and 8 ONLY (was: vmcnt(8) at every phase top).
// Ledger (per-wave, in-order vmcnt retirement; stages: P1:A1d1(t_cur+1),
// P2:A0d0(t+2), P3:B0d0, P4:B1d0, P5:A1d0, P6:A0d1(t+3), P7:B0d1, P8:B1d1):
//   P4-top vmcnt(4): outstanding {P6',P7' leftover(4)}+P8'+P1+P2+P3 = 12
//     -> retires P6',P7',P8',P1: covers P5 (needs P6',P7',P8') and P7
//     (needs P1).  Published via P4's barrier.
//   P8-top vmcnt(4): outstanding {P2,P3 leftover}+P4+P5+P6+P7 = 12
//     -> retires P2,P3,P4,P5: covers next iter's P1 (P2,P3,P4) and P3 (P5).
//   Prologue: 7 halves staged, vmcnt(6) retires first 4 (A0d0,B0d0,B1d0,
//     A1d0) = everything P1..P3 of iter 0 read.
//   Tail: P4-top vmcnt(2) (retires P6',P7',P8'), P6-top vmcnt(0) (P1t).
// Up to 12 loads in flight across barriers; never drains in main loop.
#define BM 256
#define BN 256
#define BK 64
#define NT (IN_FEATS / BK)       // 32 K-tiles, 16 iterations

__device__ inline void gload16(const unsigned short* g, unsigned short* l) {
    __builtin_amdgcn_global_load_lds(
        (const __attribute__((address_space(1))) unsigned int*)g,
        (__attribute__((address_space(3))) unsigned int*)l,
        16, 0, 0);
}

#define WAITV(N) asm volatile("s_waitcnt vmcnt(" #N ")" ::: "memory")
#define LGKM0    asm volatile("s_waitcnt lgkmcnt(0)" ::: "memory")
#define FENCE    asm volatile("" ::: "memory")
#define SBAR     do { FENCE; __builtin_amdgcn_s_barrier(); FENCE; } while (0)

__global__ __launch_bounds__(512, 2) void gemm_bt_kernel(
    const unsigned short* __restrict__ A,   // [M][K] bf16 (x)
    const unsigned short* __restrict__ B,   // [N][K] bf16 (Ht)
    const float* __restrict__ bias,         // [N]
    float* __restrict__ C)                  // [M][N] fp32
{
    constexpr int N = OUT_FEATS, K = IN_FEATS;
    // [dbuf 2][ A 16384 | B 16384 ] ushorts = 128 KiB; halves of 8192 (128 rows)
    __shared__ unsigned short LDS[65536];

    const int tid  = threadIdx.x;
    const int wave = tid >> 6;
    const int lane = tid & 63;
    const int lm16 = lane & 15;              // MFMA fragment row/col
    const int l47  = lane >> 4;              // 0..3: k-quarter selector

    const int bn = blockIdx.x;
    const int bm = blockIdx.y;

    const int wm = (wave >> 2) * 64;         // wave m-band base (interleaved)
    const int wn = (wave & 3) * 32;          // wave n-band base (interleaved)

    // ---- swizzled ds_read offsets (ushort units): slot = chunk ^ (row&7),
    // row&7 == lane&7 (all frag row bases are multiples of 16) ----
    const int aB  = (wm + lm16) * 64;                    // + FB + f*1024 + sc
    const int bB  = 16384 + (wn + lm16) * 64;
    const int sc0 = ((l47      ^ (lane & 7))) * 8;       // k2=0 chunk = l47
    const int sc1 = (((4 + l47) ^ (lane & 7))) * 8;      // k2=1 chunk = 4+l47

    // ---- staging: half-tile = 128 rows x 64 k = 1024 chunks; thread covers
    // chunks {tid, 512+tid}; row = q>>3, slot = q&7, content chunk = slot^(row&7)
    const int srow = tid >> 3;                               // 0..63 (+64 for load 1)
    const int schk = (lane & 7) ^ ((lane >> 3) & 7);
    const unsigned short* AgS = A + (size_t)(bm * BM + srow) * K + schk * 8;
    const unsigned short* BgS = B + (size_t)(bn * BN + srow) * K + schk * 8;

    // STG_X(db, h, T): stage half h of operand X, K-tile T, into dbuf db
    #define STG_A(db, h, T) do { \
        gload16(AgS + (size_t)((h) * 128)      * K + (T) * 64, LDS + (db) + (h) * 8192        + wave * 512); \
        gload16(AgS + (size_t)((h) * 128 + 64) * K + (T) * 64, LDS + (db) + (h) * 8192 + 4096 + wave * 512); } while (0)
    #define STG_B(db, h, T) do { \
        gload16(BgS + (size_t)((h) * 128)      * K + (T) * 64, LDS + 16384 + (db) + (h) * 8192        + wave * 512); \
        gload16(BgS + (size_t)((h) * 128 + 64) * K + (T) * 64, LDS + 16384 + (db) + (h) * 8192 + 4096 + wave * 512); } while (0)

    #define RD_A(D, FB) do { _Pragma("unroll") \
        for (int ff = 0; ff < 4; ++ff) { \
            a[ff][0] = *(const short8*)(LDS + (D) + aB + (FB) + ff * 1024 + sc0); \
            a[ff][1] = *(const short8*)(LDS + (D) + aB + (FB) + ff * 1024 + sc1); } } while (0)
    #define RD_B01(D) do { _Pragma("unroll") \
        for (int g = 0; g < 2; ++g) { \
            b[g][0] = *(const short8*)(LDS + (D) + bB + g * 1024 + sc0); \
            b[g][1] = *(const short8*)(LDS + (D) + bB + g * 1024 + sc1); } } while (0)
    #define RD_B23(D) do { _Pragma("unroll") \
        for (int g = 0; g < 2; ++g) { \
            b[2 + g][0] = *(const short8*)(LDS + (D) + bB + 8192 + g * 1024 + sc0); \
            b[2 + g][1] = *(const short8*)(LDS + (D) + bB + 8192 + g * 1024 + sc1); } } while (0)

    #define MM(FB, GB) do { _Pragma("unroll") \
        for (int k2 = 0; k2 < 2; ++k2) { _Pragma("unroll") \
            for (int ff = 0; ff < 4; ++ff) { _Pragma("unroll") \
                for (int g = 0; g < 2; ++g) \
                    acc[(FB) + ff][(GB) + g] = __builtin_amdgcn_mfma_f32_16x16x32_bf16( \
                        a[ff][k2], b[(GB) + g][k2], acc[(FB) + ff][(GB) + g], 0, 0, 0); } } } while (0)

    #define PH_MID do { SBAR; LGKM0; __builtin_amdgcn_sched_barrier(0); \
                        __builtin_amdgcn_s_setprio(1); } while (0)
    #define PH_END do { __builtin_amdgcn_s_setprio(0); SBAR; } while (0)

    // ---- prologue: 7 halves in consumption order (A-h1(t1) deferred to P1)
    STG_A(0, 0, 0);  STG_B(0, 0, 0);  STG_B(0, 1, 0);  STG_A(0, 1, 0);
    STG_A(32768, 0, 1);  STG_B(32768, 0, 1);  STG_B(32768, 1, 1);
    WAITV(6);                         // retires A-h0(0), B-h0(0), B-h1(0), A-h1(0)
    SBAR;

    f32x4 acc[8][4] = {};             // [m-frag][n-frag]
    short8 a[4][2], b[4][2];

    #pragma unroll 1
    for (int j = 0; j < NT / 2 - 1; ++j) {   // iters 0..14: tiles 2j (dbuf0), 2j+1 (dbuf1)
        const int t2 = 2 * j + 2, t3 = 2 * j + 3;
        // P1
        RD_A(0, 0); RD_B01(0); STG_A(32768, 1, 2 * j + 1);
        PH_MID; MM(0, 0); PH_END;
        // P2
        RD_B23(0); STG_A(0, 0, t2);
        PH_MID; MM(0, 2); PH_END;
        // P3
        RD_A(0, 8192); STG_B(0, 0, t2);
        PH_MID; MM(4, 0); PH_END;
        // P4  (counted wait #1: retires P6',P7',P8',P1 -> covers P5 and P7)
        WAITV(4); STG_B(0, 1, t2);
        PH_MID; MM(4, 2); PH_END;
        // P5
        RD_A(32768, 0); RD_B01(32768); STG_A(0, 1, t2);
        PH_MID; MM(0, 0); PH_END;
        // P6
        RD_B23(32768); STG_A(32768, 0, t3);
        PH_MID; MM(0, 2); PH_END;
        // P7
        RD_A(32768, 8192); STG_B(32768, 0, t3);
        PH_MID; MM(4, 0); PH_END;
        // P8  (counted wait #2: retires P2,P3,P4,P5 -> covers next P1 and P3)
        WAITV(4); STG_B(32768, 1, t3);
        PH_MID; MM(4, 2); PH_END;
    }

    // ---- tail iter (tiles NT-2 -> dbuf0, NT-1 -> dbuf1): only P1 stages ----
    // P1
    RD_A(0, 0); RD_B01(0); STG_A(32768, 1, NT - 1);
    PH_MID; MM(0, 0); PH_END;
    // P2
    RD_B23(0);
    PH_MID; MM(0, 2); PH_END;
    // P3
    RD_A(0, 8192);
    PH_MID; MM(4, 0); PH_END;
    // P4  (retires P6',P7',P8' -> covers P5/P6 reads)
    WAITV(2);
    PH_MID; MM(4, 2); PH_END;
    // P5
    RD_A(32768, 0); RD_B01(32768);
    PH_MID; MM(0, 0); PH_END;
    // P6  (retires P1t -> covers P7 read)
    WAITV(0); RD_B23(32768);
    PH_MID; MM(0, 2); PH_END;
    // P7
    RD_A(32768, 8192);
    PH_MID; MM(4, 0); PH_END;
    // P8
    PH_MID; MM(4, 2); PH_END;

    // epilogue: 16x16x32 C/D layout col=lane&15, row=(lane>>4)*4+reg
    #pragma unroll
    for (int g = 0; g < 4; ++g) {
        const int col = bn * BN + wn + (g >> 1) * 128 + (g & 1) * 16 + lm16;
        const float bv = bias[col];
        #pragma unroll
        for (int f = 0; f < 8; ++f) {
            const int row0 = bm * BM + wm + (f >> 2) * 128 + (f & 3) * 16 + l47 * 4;
            #pragma unroll
            for (int r = 0; r < 4; ++r)
                C[(size_t)(row0 + r) * N + col] = acc[f][g][r] + bv;
        }
    }
    #undef STG_A
    #undef STG_B
    #undef RD_A
    #undef RD_B01
    #undef RD_B23
    #undef MM
    #undef PH_MID
    #undef PH_END
}

extern "C" void kernel_launch(void* const* d_in, const int* in_sizes, int n_in,
                              void* d_out, int out_size, void* d_ws, size_t ws_size,
                              hipStream_t stream) {
    const float* x    = (const float*)d_in[0];   // [8192][2048]
    const float* rule = (const float*)d_in[1];   // [4][4][4]
    const float* W    = (const float*)d_in[2];   // [4][512][2048]
    const float* b    = (const float*)d_in[3];   // [8192]
    float* y = (float*)d_out;                    // [8192][8192]

    unsigned short* xb = (unsigned short*)d_ws;                       // 32 MB
    unsigned short* Ht = (unsigned short*)((char*)d_ws +
                         (size_t)TOKENS * IN_FEATS * sizeof(unsigned short)); // 32 MB

    prep_kernel<<<BUILD_BLOCKS + CVT_BLOCKS, 256, 0, stream>>>(x, xb, rule, W, Ht);
    gemm_bt_kernel<<<dim3(OUT_FEATS / BN, TOKENS / BM), 512, 0, stream>>>(xb, Ht, b, y);
}